// Round 5
// baseline (12189.634 us; speedup 1.0000x reference)
//
#include <hip/hip_runtime.h>

// Problem constants
#define NB 256   // batch
#define TT 256   // time steps
#define II 512   // input dim
#define HH 512   // hidden dim
#define GG 1536  // 3*H gates

typedef unsigned short ushort_t;
typedef unsigned int uint_t;
typedef __attribute__((ext_vector_type(8))) short short8;   // 8 x bf16 (4 VGPRs)
typedef __attribute__((ext_vector_type(4))) float f32x4;    // MFMA accumulator

typedef __attribute__((address_space(3))) void lds_void;
typedef const __attribute__((address_space(1))) void glb_void;

__device__ __forceinline__ ushort_t f2bf(float f) {
  union { float f; unsigned int u; } x; x.f = f;
  unsigned int r = x.u + 0x7FFFu + ((x.u >> 16) & 1u);  // RNE
  return (ushort_t)(r >> 16);
}
__device__ __forceinline__ float bf2f(ushort_t b) {
  union { unsigned int u; float f; } x; x.u = ((unsigned int)b) << 16;
  return x.f;
}
__device__ __forceinline__ float sigmoidf_(float x) {
  return __fdividef(1.0f, 1.0f + __expf(-x));
}
__device__ __forceinline__ float tanhf_(float x) {
  float t = __expf(2.0f * x);
  return 1.0f - __fdividef(2.0f, t + 1.0f);
}
__device__ __forceinline__ short8 pack8(float4 a, float4 b) {
  short8 r;
  r[0] = (short)f2bf(a.x); r[1] = (short)f2bf(a.y);
  r[2] = (short)f2bf(a.z); r[3] = (short)f2bf(a.w);
  r[4] = (short)f2bf(b.x); r[5] = (short)f2bf(b.y);
  r[6] = (short)f2bf(b.z); r[7] = (short)f2bf(b.w);
  return r;
}

// ---------------------------------------------------------------------------
// is_init canonicalization -> uint8 mask (handles u8/i32/f32/i64 storage).
__global__ void mask_detect_kernel(const unsigned char* __restrict__ src,
                                   unsigned char* __restrict__ mask8) {
  __shared__ int fByte, fOdd;
  const int tid = threadIdx.x;
  if (tid == 0) { fByte = 0; fOdd = 0; }
  __syncthreads();
  const uint_t* w = (const uint_t*)src;
  int ab = 0, ao = 0;
  for (int i = tid; i < NB * TT; i += blockDim.x) {
    if ((i & 3) == 1 && src[i]) ab = 1;
    if (i < 16384 && (i & 1) == 1 && w[i]) ao = 1;
  }
  if (ab) fByte = 1;
  if (ao) fOdd = 1;
  __syncthreads();
  const int isByte = fByte, isW32 = fOdd;
  for (int i = tid; i < NB * TT; i += blockDim.x) {
    unsigned char m;
    if (isByte)      m = src[i] ? 1 : 0;
    else if (isW32)  m = w[i] ? 1 : 0;
    else             m = w[2 * i] ? 1 : 0;
    mask8[i] = m;
  }
}

// ---------------------------------------------------------------------------
__global__ void cvt_f2bf(const float* __restrict__ src, ushort_t* __restrict__ dst,
                         int n4) {
  int stride = gridDim.x * blockDim.x;
  for (int i = blockIdx.x * blockDim.x + threadIdx.x; i < n4; i += stride) {
    const float4 v = reinterpret_cast<const float4*>(src)[i];
    ushort4 o;
    o.x = f2bf(v.x); o.y = f2bf(v.y); o.z = f2bf(v.z); o.w = f2bf(v.w);
    reinterpret_cast<ushort4*>(dst)[i] = o;
  }
}

// ---------------------------------------------------------------------------
// Pack W_hh [1536][512] f32 into MFMA-B-fragment order (bf16):
// Wpk[((tile*16+kk)*64 + lane)*8 + e] = W[tile*16 + (lane&15)][kk*32 + (lane>>4)*8 + e]
__global__ void pack_whh(const float* __restrict__ W, ushort_t* __restrict__ out) {
  int idx = blockIdx.x * blockDim.x + threadIdx.x;  // 96*16*64 = 98304
  if (idx >= 96 * 16 * 64) return;
  int l = idx & 63;
  int tk = idx >> 6;
  int tile = tk >> 4, kk = tk & 15;
  int row = tile * 16 + (l & 15);
  int k = kk * 32 + (l >> 4) * 8;
  const float* s = W + (size_t)row * HH + k;
  short8 v;
#pragma unroll
  for (int e = 0; e < 8; ++e) v[e] = (short)f2bf(s[e]);
  *reinterpret_cast<short8*>(out + (size_t)idx * 8) = v;
}

// ---------------------------------------------------------------------------
// GEMM: C[m][c] = sum_k A[m][k]*B[c][k] + bias[c].  (unchanged)
template <int AF32, int CF32>
__global__ __launch_bounds__(256) void gemm_bt(
    const void* __restrict__ Av, const ushort_t* __restrict__ B,
    const float* __restrict__ bias, void* __restrict__ Cv, int NC) {
  __shared__ ushort_t As[128 * 32];
  __shared__ ushort_t Bs[128 * 32];
  const int tid = threadIdx.x;
  const int lane = tid & 63;
  const int w = tid >> 6;
  const int wr = w >> 1, wc = w & 1;
  const int c15 = lane & 15, l4 = lane >> 4;
  const int mbase = blockIdx.x * 128;
  const int nbase = blockIdx.y * 128;

  const int rs = tid >> 2;
  const int kb = (tid & 3) * 8;

  f32x4 acc[4][4] = {};

  const float4* Bg = reinterpret_cast<const float4*>(B);
  auto bIdx = [&](int c, int kt) {
    return ((size_t)(nbase + rs + 64 * c) * 512 + kt * 32 + kb) >> 3;
  };
  float4 rb0 = Bg[bIdx(0, 0)], rb1 = Bg[bIdx(1, 0)];

  const float4* Agf = reinterpret_cast<const float4*>(Av);
  auto aEl = [&](int c, int kt) {
    return (size_t)(mbase + rs + 64 * c) * 512 + kt * 32 + kb;
  };
  float4 a0a, a0b, a1a, a1b;
  float4 h0, h1;
  if constexpr (AF32) {
    a0a = Agf[aEl(0, 0) >> 2]; a0b = Agf[(aEl(0, 0) >> 2) + 1];
    a1a = Agf[aEl(1, 0) >> 2]; a1b = Agf[(aEl(1, 0) >> 2) + 1];
  } else {
    h0 = Agf[aEl(0, 0) >> 3];
    h1 = Agf[aEl(1, 0) >> 3];
  }

  for (int kt = 0; kt < 16; ++kt) {
    __syncthreads();
    if constexpr (AF32) {
      *reinterpret_cast<short8*>(&As[(size_t)tid * 8]) = pack8(a0a, a0b);
      *reinterpret_cast<short8*>(&As[(size_t)(tid + 256) * 8]) = pack8(a1a, a1b);
    } else {
      reinterpret_cast<float4*>(As)[tid] = h0;
      reinterpret_cast<float4*>(As)[tid + 256] = h1;
    }
    reinterpret_cast<float4*>(Bs)[tid] = rb0;
    reinterpret_cast<float4*>(Bs)[tid + 256] = rb1;
    if (kt < 15) {
      if constexpr (AF32) {
        a0a = Agf[aEl(0, kt + 1) >> 2]; a0b = Agf[(aEl(0, kt + 1) >> 2) + 1];
        a1a = Agf[aEl(1, kt + 1) >> 2]; a1b = Agf[(aEl(1, kt + 1) >> 2) + 1];
      } else {
        h0 = Agf[aEl(0, kt + 1) >> 3];
        h1 = Agf[aEl(1, kt + 1) >> 3];
      }
      rb0 = Bg[bIdx(0, kt + 1)]; rb1 = Bg[bIdx(1, kt + 1)];
    }
    __syncthreads();
    short8 af[4], bq[4];
#pragma unroll
    for (int m = 0; m < 4; ++m)
      af[m] = *reinterpret_cast<const short8*>(&As[(wr * 64 + m * 16 + c15) * 32 + l4 * 8]);
#pragma unroll
    for (int n = 0; n < 4; ++n)
      bq[n] = *reinterpret_cast<const short8*>(&Bs[(wc * 64 + n * 16 + c15) * 32 + l4 * 8]);
#pragma unroll
    for (int m = 0; m < 4; ++m)
#pragma unroll
      for (int n = 0; n < 4; ++n)
        acc[m][n] = __builtin_amdgcn_mfma_f32_16x16x32_bf16(af[m], bq[n], acc[m][n], 0, 0, 0);
  }

#pragma unroll
  for (int n = 0; n < 4; ++n) {
    const int col = nbase + wc * 64 + n * 16 + c15;
    const float bv = bias[col];
#pragma unroll
    for (int m = 0; m < 4; ++m) {
      const int row = mbase + wr * 64 + m * 16 + l4 * 4;
#pragma unroll
      for (int q = 0; q < 4; ++q) {
        const float v = acc[m][n][q] + bv;
        if constexpr (CF32)
          reinterpret_cast<float*>(Cv)[(size_t)(row + q) * NC + col] = v;
        else
          reinterpret_cast<ushort_t*>(Cv)[(size_t)(row + q) * NC + col] = f2bf(v);
      }
    }
  }
}

// ---------------------------------------------------------------------------
// GRU recurrence v3. 16 blocks x 1024 threads (16 waves, 4/SIMD, 1 block/CU).
// __launch_bounds__(1024,4) -> 128 VGPR cap (R4's 64-cap spilled everything).
// xi[t] staged via global_load_lds (no VGPR cost) with pre-swizzled SOURCE
// chunks; reader XORs the same involution -> conflict-free phase-C reads.
__global__ __launch_bounds__(1024, 4) void gru_rec(
    const ushort_t* __restrict__ xi, const ushort_t* __restrict__ Wpk,
    const float* __restrict__ hx, const float* __restrict__ bhh,
    const unsigned char* __restrict__ mask8,
    ushort_t* __restrict__ hs, float* __restrict__ hT) {
  __shared__ ushort_t hB[16 * 512];    // bf16 h, XOR-swizzled rows (16 KB)
  __shared__ ushort_t xiL[16 * 1536];  // xi[t] staging, swizzled (48 KB)
  const int tid = threadIdx.x;
  const int lane = tid & 63;
  const int w = tid >> 6;              // wave 0..15 -> j-slice w*32
  const int c15 = lane & 15, l4 = lane >> 4;
  const int n0 = blockIdx.x * 16;

  // hB byte-offset with XOR swizzle (row stride 1024B = 16-way conflict raw)
  auto hbOff = [](int row, int colByte) {
    return row * 1024 + (colByte ^ ((row & 7) << 4));
  };
  // xiL read swizzle (ushort units): element (s, gj) at s*1536 + (gj ^ P(s)<<3)
  auto xiOff = [](int s, int gj) {
    return s * 1536 + (gj ^ (((s >> 1) & 7) << 3));
  };

  // per-thread ownership: samples s(q)=l4*4+q, cols J(t2)=w*32+t2*16+c15
  int J[2];  float br[2], bz[2], bn[2];
#pragma unroll
  for (int t2 = 0; t2 < 2; ++t2) {
    J[t2] = w * 32 + t2 * 16 + c15;
    br[t2] = bhh[J[t2]];
    bz[t2] = bhh[512 + J[t2]];
    bn[t2] = bhh[1024 + J[t2]];
  }

  // W_hh fragment base offsets (ushort units): tile(i) = (i>>1)*32 + w*2 + (i&1)
  int Bbase[6];
#pragma unroll
  for (int i = 0; i < 6; ++i) {
    const int tile = (i >> 1) * 32 + w * 2 + (i & 1);
    Bbase[i] = tile * 8192 + lane * 8;   // ((tile*16+kk)*64+lane)*8, kk=0
  }

  // xi DMA geometry: 3072 16B-chunks/step = [16 rows][192 chunks]; 3/thread.
  // LDS dest is LINEAR chunk c*16B (global_load_lds requirement, m104);
  // the SOURCE chunk is pre-permuted so reads with xiOff() see logical data.
  size_t xgBase[3];
  int xlChunk[3];
#pragma unroll
  for (int k = 0; k < 3; ++k) {
    const int c = tid + k * 1024;
    const int sK = c / 192, ch = c % 192;
    const int chSrc = ch ^ ((sK >> 1) & 7);          // T21 source pre-swizzle
    xgBase[k] = (size_t)(n0 + sK) * TT * GG + chSrc * 8;  // + t*GG per step
    xlChunk[k] = c * 8;                               // ushort offset in xiL
  }

  // init h regs + hB (mask[0] applied)
  float h[2][4];
#pragma unroll
  for (int q = 0; q < 4; ++q) {
    const int s = l4 * 4 + q;
    const bool mk0 = mask8[(size_t)(n0 + s) * TT] != 0;
#pragma unroll
    for (int t2 = 0; t2 < 2; ++t2) {
      float v = mk0 ? 0.0f : hx[(size_t)(n0 + s) * TT * HH + J[t2]];
      h[t2][q] = v;
      *(ushort_t*)((char*)hB + hbOff(s, J[t2] * 2)) = f2bf(v);
    }
  }
  __syncthreads();

  for (int t = 0; t < TT; ++t) {
    // ---- phase B: issue xi DMA first (oldest vmcnt), then MFMA w/ W dbuf
#pragma unroll
    for (int k = 0; k < 3; ++k)
      __builtin_amdgcn_global_load_lds(
          (glb_void*)(xi + xgBase[k] + (size_t)t * GG),
          (lds_void*)(xiL + xlChunk[k]), 16, 0, 0);

    // prefetch next-step mask bytes
    const int tn = (t + 1 < TT) ? (t + 1) : t;
    unsigned char mkv[4];
#pragma unroll
    for (int q = 0; q < 4; ++q)
      mkv[q] = mask8[(size_t)(n0 + l4 * 4 + q) * TT + tn];

    f32x4 acc[6];
#pragma unroll
    for (int i = 0; i < 6; ++i) acc[i] = (f32x4){0.f, 0.f, 0.f, 0.f};

    short8 a0, a1, b0[6], b1[6];
    a0 = *(const short8*)((char*)hB + hbOff(c15, l4 * 16));
#pragma unroll
    for (int i = 0; i < 6; ++i) b0[i] = *(const short8*)(Wpk + Bbase[i]);

#pragma unroll
    for (int kk = 0; kk < 16; ++kk) {
      if (kk < 15) {
        if (kk & 1) {
          a0 = *(const short8*)((char*)hB + hbOff(c15, (kk + 1) * 64 + l4 * 16));
#pragma unroll
          for (int i = 0; i < 6; ++i)
            b0[i] = *(const short8*)(Wpk + Bbase[i] + (kk + 1) * 512);
        } else {
          a1 = *(const short8*)((char*)hB + hbOff(c15, (kk + 1) * 64 + l4 * 16));
#pragma unroll
          for (int i = 0; i < 6; ++i)
            b1[i] = *(const short8*)(Wpk + Bbase[i] + (kk + 1) * 512);
        }
      }
      if (kk & 1) {
#pragma unroll
        for (int i = 0; i < 6; ++i)
          acc[i] = __builtin_amdgcn_mfma_f32_16x16x32_bf16(a1, b1[i], acc[i], 0, 0, 0);
      } else {
#pragma unroll
        for (int i = 0; i < 6; ++i)
          acc[i] = __builtin_amdgcn_mfma_f32_16x16x32_bf16(a0, b0[i], acc[i], 0, 0, 0);
      }
    }
    __syncthreads();   // compiler drains vmcnt(0) first -> xiL DMA complete

    // ---- phase C: gates + h update (h regs), write hB for next step + hs
    const bool domask = (t + 1 < TT);
#pragma unroll
    for (int t2 = 0; t2 < 2; ++t2) {
      const int Jt = J[t2];
#pragma unroll
      for (int q = 0; q < 4; ++q) {
        const int s = l4 * 4 + q;
        const float xr = bf2f(xiL[xiOff(s, Jt)]);
        const float xz = bf2f(xiL[xiOff(s, 512 + Jt)]);
        const float xn = bf2f(xiL[xiOff(s, 1024 + Jt)]);
        const float rr = sigmoidf_(xr + acc[t2][q] + br[t2]);
        const float zz = sigmoidf_(xz + acc[2 + t2][q] + bz[t2]);
        const float nn = tanhf_(xn + rr * (acc[4 + t2][q] + bn[t2]));
        const float hnew = (1.0f - zz) * nn + zz * h[t2][q];
        hs[((size_t)(n0 + s) * TT + t) * HH + Jt] = f2bf(hnew);
        const float hnext = (domask && mkv[q]) ? 0.0f : hnew;
        h[t2][q] = hnext;
        *(ushort_t*)((char*)hB + hbOff(s, Jt * 2)) = f2bf(hnext);
      }
    }
    __syncthreads();
  }

  // epilogue: hT (f32) for hx_out broadcast
#pragma unroll
  for (int t2 = 0; t2 < 2; ++t2)
#pragma unroll
    for (int q = 0; q < 4; ++q)
      hT[(size_t)(n0 + l4 * 4 + q) * HH + J[t2]] = h[t2][q];
}

// ---------------------------------------------------------------------------
// hx_out[n,t,:] = hT[n,:]  (f32, overwrites the hs scratch region after gemm3)
__global__ void bcast_hT(const float* __restrict__ hT, float* __restrict__ dst) {
  const float4* s = (const float4*)hT;
  float4* d = (float4*)dst;
  const int total = NB * TT * HH / 4;
  const int stride = gridDim.x * blockDim.x;
  for (int c = blockIdx.x * blockDim.x + threadIdx.x; c < total; c += stride) {
    int n = c >> 15;
    int j4 = c & 127;
    d[c] = s[(n << 7) | j4];
  }
}

// ---------------------------------------------------------------------------
extern "C" void kernel_launch(void* const* d_in, const int* in_sizes, int n_in,
                              void* d_out, int out_size, void* d_ws, size_t ws_size,
                              hipStream_t stream) {
  const float* x    = (const float*)d_in[0];
  const float* hx   = (const float*)d_in[1];
  const float* Wih  = (const float*)d_in[2];
  const float* Whh  = (const float*)d_in[3];
  const float* bih  = (const float*)d_in[4];
  const float* bhh  = (const float*)d_in[5];
  const float* Wout = (const float*)d_in[6];
  const float* bout = (const float*)d_in[7];
  const unsigned char* isinit = (const unsigned char*)d_in[8];

  char* ws = (char*)d_ws;
  ushort_t* xi    = (ushort_t*)(ws);
  ushort_t* wihb  = (ushort_t*)(ws + 201326592);
  ushort_t* whhp  = (ushort_t*)(ws + 202899456);
  ushort_t* woutb = (ushort_t*)(ws + 204472320);
  unsigned char* mask8 = (unsigned char*)(ws + 204996608);
  float*    hTbuf = (float*)(ws + 205062144);

  float* out1 = (float*)d_out;                       // output [N,T,H] f32
  float* out2 = out1 + (size_t)NB * TT * HH;         // hx_out [N,T,H] f32
  ushort_t* hsb = (ushort_t*)out2;  // hs bf16 scratch until bcast overwrites

  mask_detect_kernel<<<1, 1024, 0, stream>>>(isinit, mask8);
  cvt_f2bf<<<768, 256, 0, stream>>>(Wih, wihb, GG * II / 4);
  cvt_f2bf<<<256, 256, 0, stream>>>(Wout, woutb, HH * HH / 4);
  pack_whh<<<384, 256, 0, stream>>>(Whh, whhp);

  dim3 g1(512, 12);  // M/128 x 3H/128
  gemm_bt<1, 0><<<g1, 256, 0, stream>>>((const void*)x, wihb, bih, (void*)xi, GG);

  gru_rec<<<16, 1024, 0, stream>>>(xi, whhp, hx, bhh, mask8, hsb, hTbuf);

  dim3 g3(512, 4);   // M/128 x H/128
  gemm_bt<0, 1><<<g3, 256, 0, stream>>>((const void*)hsb, woutb, bout, (void*)out1, HH);

  bcast_hT<<<2048, 256, 0, stream>>>(hTbuf, out2);
}

// Round 6
// 11967.493 us; speedup vs baseline: 1.0186x; 1.0186x over previous
//
#include <hip/hip_runtime.h>

// Problem constants
#define NB 256   // batch
#define TT 256   // time steps
#define II 512   // input dim
#define HH 512   // hidden dim
#define GG 1536  // 3*H gates

typedef unsigned short ushort_t;
typedef unsigned int uint_t;
typedef __attribute__((ext_vector_type(8))) short short8;   // 8 x bf16 (4 VGPRs)
typedef __attribute__((ext_vector_type(4))) float f32x4;    // MFMA accumulator

typedef __attribute__((address_space(3))) void lds_void;
typedef const __attribute__((address_space(1))) void glb_void;

__device__ __forceinline__ ushort_t f2bf(float f) {
  union { float f; unsigned int u; } x; x.f = f;
  unsigned int r = x.u + 0x7FFFu + ((x.u >> 16) & 1u);  // RNE
  return (ushort_t)(r >> 16);
}
__device__ __forceinline__ float bf2f(ushort_t b) {
  union { unsigned int u; float f; } x; x.u = ((unsigned int)b) << 16;
  return x.f;
}
__device__ __forceinline__ float sigmoidf_(float x) {
  return __fdividef(1.0f, 1.0f + __expf(-x));
}
__device__ __forceinline__ float tanhf_(float x) {
  float t = __expf(2.0f * x);
  return 1.0f - __fdividef(2.0f, t + 1.0f);
}
__device__ __forceinline__ short8 pack8(float4 a, float4 b) {
  short8 r;
  r[0] = (short)f2bf(a.x); r[1] = (short)f2bf(a.y);
  r[2] = (short)f2bf(a.z); r[3] = (short)f2bf(a.w);
  r[4] = (short)f2bf(b.x); r[5] = (short)f2bf(b.y);
  r[6] = (short)f2bf(b.z); r[7] = (short)f2bf(b.w);
  return r;
}

// ---------------------------------------------------------------------------
// is_init canonicalization -> uint8 mask (handles u8/i32/f32/i64 storage).
__global__ void mask_detect_kernel(const unsigned char* __restrict__ src,
                                   unsigned char* __restrict__ mask8) {
  __shared__ int fByte, fOdd;
  const int tid = threadIdx.x;
  if (tid == 0) { fByte = 0; fOdd = 0; }
  __syncthreads();
  const uint_t* w = (const uint_t*)src;
  int ab = 0, ao = 0;
  for (int i = tid; i < NB * TT; i += blockDim.x) {
    if ((i & 3) == 1 && src[i]) ab = 1;
    if (i < 16384 && (i & 1) == 1 && w[i]) ao = 1;
  }
  if (ab) fByte = 1;
  if (ao) fOdd = 1;
  __syncthreads();
  const int isByte = fByte, isW32 = fOdd;
  for (int i = tid; i < NB * TT; i += blockDim.x) {
    unsigned char m;
    if (isByte)      m = src[i] ? 1 : 0;
    else if (isW32)  m = w[i] ? 1 : 0;
    else             m = w[2 * i] ? 1 : 0;
    mask8[i] = m;
  }
}

// ---------------------------------------------------------------------------
__global__ void cvt_f2bf(const float* __restrict__ src, ushort_t* __restrict__ dst,
                         int n4) {
  int stride = gridDim.x * blockDim.x;
  for (int i = blockIdx.x * blockDim.x + threadIdx.x; i < n4; i += stride) {
    const float4 v = reinterpret_cast<const float4*>(src)[i];
    ushort4 o;
    o.x = f2bf(v.x); o.y = f2bf(v.y); o.z = f2bf(v.z); o.w = f2bf(v.w);
    reinterpret_cast<ushort4*>(dst)[i] = o;
  }
}

// ---------------------------------------------------------------------------
// Pack W_hh [1536][512] f32 into MFMA-B-fragment order (bf16):
// Wpk[((tile*16+kk)*64 + lane)*8 + e] = W[tile*16 + (lane&15)][kk*32 + (lane>>4)*8 + e]
__global__ void pack_whh(const float* __restrict__ W, ushort_t* __restrict__ out) {
  int idx = blockIdx.x * blockDim.x + threadIdx.x;  // 96*16*64 = 98304
  if (idx >= 96 * 16 * 64) return;
  int l = idx & 63;
  int tk = idx >> 6;
  int tile = tk >> 4, kk = tk & 15;
  int row = tile * 16 + (l & 15);
  int k = kk * 32 + (l >> 4) * 8;
  const float* s = W + (size_t)row * HH + k;
  short8 v;
#pragma unroll
  for (int e = 0; e < 8; ++e) v[e] = (short)f2bf(s[e]);
  *reinterpret_cast<short8*>(out + (size_t)idx * 8) = v;
}

// ---------------------------------------------------------------------------
// GEMM: C[m][c] = sum_k A[m][k]*B[c][k] + bias[c].  (unchanged)
template <int AF32, int CF32>
__global__ __launch_bounds__(256) void gemm_bt(
    const void* __restrict__ Av, const ushort_t* __restrict__ B,
    const float* __restrict__ bias, void* __restrict__ Cv, int NC) {
  __shared__ ushort_t As[128 * 32];
  __shared__ ushort_t Bs[128 * 32];
  const int tid = threadIdx.x;
  const int lane = tid & 63;
  const int w = tid >> 6;
  const int wr = w >> 1, wc = w & 1;
  const int c15 = lane & 15, l4 = lane >> 4;
  const int mbase = blockIdx.x * 128;
  const int nbase = blockIdx.y * 128;

  const int rs = tid >> 2;
  const int kb = (tid & 3) * 8;

  f32x4 acc[4][4] = {};

  const float4* Bg = reinterpret_cast<const float4*>(B);
  auto bIdx = [&](int c, int kt) {
    return ((size_t)(nbase + rs + 64 * c) * 512 + kt * 32 + kb) >> 3;
  };
  float4 rb0 = Bg[bIdx(0, 0)], rb1 = Bg[bIdx(1, 0)];

  const float4* Agf = reinterpret_cast<const float4*>(Av);
  auto aEl = [&](int c, int kt) {
    return (size_t)(mbase + rs + 64 * c) * 512 + kt * 32 + kb;
  };
  float4 a0a, a0b, a1a, a1b;
  float4 h0, h1;
  if constexpr (AF32) {
    a0a = Agf[aEl(0, 0) >> 2]; a0b = Agf[(aEl(0, 0) >> 2) + 1];
    a1a = Agf[aEl(1, 0) >> 2]; a1b = Agf[(aEl(1, 0) >> 2) + 1];
  } else {
    h0 = Agf[aEl(0, 0) >> 3];
    h1 = Agf[aEl(1, 0) >> 3];
  }

  for (int kt = 0; kt < 16; ++kt) {
    __syncthreads();
    if constexpr (AF32) {
      *reinterpret_cast<short8*>(&As[(size_t)tid * 8]) = pack8(a0a, a0b);
      *reinterpret_cast<short8*>(&As[(size_t)(tid + 256) * 8]) = pack8(a1a, a1b);
    } else {
      reinterpret_cast<float4*>(As)[tid] = h0;
      reinterpret_cast<float4*>(As)[tid + 256] = h1;
    }
    reinterpret_cast<float4*>(Bs)[tid] = rb0;
    reinterpret_cast<float4*>(Bs)[tid + 256] = rb1;
    if (kt < 15) {
      if constexpr (AF32) {
        a0a = Agf[aEl(0, kt + 1) >> 2]; a0b = Agf[(aEl(0, kt + 1) >> 2) + 1];
        a1a = Agf[aEl(1, kt + 1) >> 2]; a1b = Agf[(aEl(1, kt + 1) >> 2) + 1];
      } else {
        h0 = Agf[aEl(0, kt + 1) >> 3];
        h1 = Agf[aEl(1, kt + 1) >> 3];
      }
      rb0 = Bg[bIdx(0, kt + 1)]; rb1 = Bg[bIdx(1, kt + 1)];
    }
    __syncthreads();
    short8 af[4], bq[4];
#pragma unroll
    for (int m = 0; m < 4; ++m)
      af[m] = *reinterpret_cast<const short8*>(&As[(wr * 64 + m * 16 + c15) * 32 + l4 * 8]);
#pragma unroll
    for (int n = 0; n < 4; ++n)
      bq[n] = *reinterpret_cast<const short8*>(&Bs[(wc * 64 + n * 16 + c15) * 32 + l4 * 8]);
#pragma unroll
    for (int m = 0; m < 4; ++m)
#pragma unroll
      for (int n = 0; n < 4; ++n)
        acc[m][n] = __builtin_amdgcn_mfma_f32_16x16x32_bf16(af[m], bq[n], acc[m][n], 0, 0, 0);
  }

#pragma unroll
  for (int n = 0; n < 4; ++n) {
    const int col = nbase + wc * 64 + n * 16 + c15;
    const float bv = bias[col];
#pragma unroll
    for (int m = 0; m < 4; ++m) {
      const int row = mbase + wr * 64 + m * 16 + l4 * 4;
#pragma unroll
      for (int q = 0; q < 4; ++q) {
        const float v = acc[m][n][q] + bv;
        if constexpr (CF32)
          reinterpret_cast<float*>(Cv)[(size_t)(row + q) * NC + col] = v;
        else
          reinterpret_cast<ushort_t*>(Cv)[(size_t)(row + q) * NC + col] = f2bf(v);
      }
    }
  }
}

// ---------------------------------------------------------------------------
// GRU recurrence v4. 16 blocks x 512 threads (8 waves, 2/SIMD -> 256-reg cap,
// no spills; R4/R5's 1024-thread config capped at 128 regs and spilled).
// Wave w owns hidden cols [w*64,(w+1)*64) x 3 gates = 12 MFMA tiles.
// h in registers; W reg-double-buffered; xi staged via global_load_lds into
// DOUBLE-buffered LDS (fixes t/t+1 race), source pre-swizzled (T21).
__global__ __launch_bounds__(512, 2) void gru_rec(
    const ushort_t* __restrict__ xi, const ushort_t* __restrict__ Wpk,
    const float* __restrict__ hx, const float* __restrict__ bhh,
    const unsigned char* __restrict__ mask8,
    ushort_t* __restrict__ hs, float* __restrict__ hT) {
  extern __shared__ ushort_t smem[];          // 112 KB dynamic
  ushort_t* xiL0 = smem;                      // 16*1536 = 24576 ushorts
  ushort_t* xiL1 = smem + 24576;
  ushort_t* hB   = smem + 49152;              // 16*512 ushorts, swizzled
  const int tid = threadIdx.x;
  const int lane = tid & 63;
  const int w = tid >> 6;              // wave 0..7 -> j-slice w*64
  const int c15 = lane & 15, l4 = lane >> 4;
  const int n0 = blockIdx.x * 16;

  // hB byte-offset swizzle (row stride 1024B would be 16-way conflicted raw)
  auto hbOff = [](int row, int colByte) {
    return row * 1024 + (colByte ^ ((row & 7) << 4));
  };
  // xiL read swizzle (ushort units); matches the pre-swizzled DMA source
  auto xiOff = [](int s, int gj) {
    return s * 1536 + (gj ^ (((s >> 1) & 7) << 3));
  };

  // ownership: samples s(q)=l4*4+q; cols J(t4)=w*64+t4*16+c15
  int J[4];  float br[4], bz[4], bn[4];
#pragma unroll
  for (int t4 = 0; t4 < 4; ++t4) {
    J[t4] = w * 64 + t4 * 16 + c15;
    br[t4] = bhh[J[t4]];
    bz[t4] = bhh[512 + J[t4]];
    bn[t4] = bhh[1024 + J[t4]];
  }

  // W fragment bases: tile(g,t4) = g*32 + w*4 + t4, i = g*4+t4
  int Bbase[12];
#pragma unroll
  for (int g = 0; g < 3; ++g)
#pragma unroll
    for (int t4 = 0; t4 < 4; ++t4)
      Bbase[g * 4 + t4] = (g * 32 + w * 4 + t4) * 8192 + lane * 8;

  // xi DMA: 3072 16B-chunks/step, 6 per thread; LDS dest linear in chunk id
  // (wave base + lane*16 reproduces it); global source pre-swizzled.
  size_t xgBase[6];
  int xlChunk[6];
#pragma unroll
  for (int k = 0; k < 6; ++k) {
    const int c = tid + k * 512;
    const int sK = c / 192, ch = c % 192;
    const int chSrc = ch ^ ((sK >> 1) & 7);
    xgBase[k] = (size_t)(n0 + sK) * TT * GG + chSrc * 8;
    xlChunk[k] = c * 8;
  }

  // init h regs + hB (mask[0] applied)
  float h[4][4];
#pragma unroll
  for (int q = 0; q < 4; ++q) {
    const int s = l4 * 4 + q;
    const bool mk0 = mask8[(size_t)(n0 + s) * TT] != 0;
#pragma unroll
    for (int t4 = 0; t4 < 4; ++t4) {
      float v = mk0 ? 0.0f : hx[(size_t)(n0 + s) * TT * HH + J[t4]];
      h[t4][q] = v;
      *(ushort_t*)((char*)hB + hbOff(s, J[t4] * 2)) = f2bf(v);
    }
  }
  // prologue: DMA xi[0] into buf0
#pragma unroll
  for (int k = 0; k < 6; ++k)
    __builtin_amdgcn_global_load_lds((glb_void*)(xi + xgBase[k]),
                                     (lds_void*)(xiL0 + xlChunk[k]), 16, 0, 0);
  __syncthreads();

  for (int t = 0; t < TT; ++t) {
    // ---- issue next step's xi DMA into the other buffer (t+1 race-free)
    if (t + 1 < TT) {
      ushort_t* nbuf = ((t + 1) & 1) ? xiL1 : xiL0;
#pragma unroll
      for (int k = 0; k < 6; ++k)
        __builtin_amdgcn_global_load_lds(
            (glb_void*)(xi + xgBase[k] + (size_t)(t + 1) * GG),
            (lds_void*)(nbuf + xlChunk[k]), 16, 0, 0);
    }
    // next-step mask bytes
    const int tn = (t + 1 < TT) ? (t + 1) : t;
    unsigned char mkv[4];
#pragma unroll
    for (int q = 0; q < 4; ++q)
      mkv[q] = mask8[(size_t)(n0 + l4 * 4 + q) * TT + tn];

    // ---- phase B: hh MFMA, W double-buffered in registers
    f32x4 acc[12];
#pragma unroll
    for (int i = 0; i < 12; ++i) acc[i] = (f32x4){0.f, 0.f, 0.f, 0.f};

    short8 a0, a1, b0[12], b1[12];
    a0 = *(const short8*)((char*)hB + hbOff(c15, l4 * 16));
#pragma unroll
    for (int i = 0; i < 12; ++i) b0[i] = *(const short8*)(Wpk + Bbase[i]);

#pragma unroll
    for (int kk = 0; kk < 16; ++kk) {
      if (kk < 15) {
        if (kk & 1) {
          a0 = *(const short8*)((char*)hB + hbOff(c15, (kk + 1) * 64 + l4 * 16));
#pragma unroll
          for (int i = 0; i < 12; ++i)
            b0[i] = *(const short8*)(Wpk + Bbase[i] + (kk + 1) * 512);
        } else {
          a1 = *(const short8*)((char*)hB + hbOff(c15, (kk + 1) * 64 + l4 * 16));
#pragma unroll
          for (int i = 0; i < 12; ++i)
            b1[i] = *(const short8*)(Wpk + Bbase[i] + (kk + 1) * 512);
        }
      }
      if (kk & 1) {
#pragma unroll
        for (int i = 0; i < 12; ++i)
          acc[i] = __builtin_amdgcn_mfma_f32_16x16x32_bf16(a1, b1[i], acc[i], 0, 0, 0);
      } else {
#pragma unroll
        for (int i = 0; i < 12; ++i)
          acc[i] = __builtin_amdgcn_mfma_f32_16x16x32_bf16(a0, b0[i], acc[i], 0, 0, 0);
      }
    }
    __syncthreads();   // drains DMA(t [prologue] / t+1), hB reads complete

    // ---- phase C: gates + h update, write hB (next step) + hs
    const ushort_t* xb = (t & 1) ? xiL1 : xiL0;
    const bool domask = (t + 1 < TT);
#pragma unroll
    for (int t4 = 0; t4 < 4; ++t4) {
      const int Jt = J[t4];
#pragma unroll
      for (int q = 0; q < 4; ++q) {
        const int s = l4 * 4 + q;
        const float xr = bf2f(xb[xiOff(s, Jt)]);
        const float xz = bf2f(xb[xiOff(s, 512 + Jt)]);
        const float xn = bf2f(xb[xiOff(s, 1024 + Jt)]);
        const float rr = sigmoidf_(xr + acc[t4][q] + br[t4]);
        const float zz = sigmoidf_(xz + acc[4 + t4][q] + bz[t4]);
        const float nn = tanhf_(xn + rr * (acc[8 + t4][q] + bn[t4]));
        const float hnew = (1.0f - zz) * nn + zz * h[t4][q];
        hs[((size_t)(n0 + s) * TT + t) * HH + Jt] = f2bf(hnew);
        const float hnext = (domask && mkv[q]) ? 0.0f : hnew;
        h[t4][q] = hnext;
        *(ushort_t*)((char*)hB + hbOff(s, Jt * 2)) = f2bf(hnext);
      }
    }
    __syncthreads();
  }

  // epilogue: hT (f32) for hx_out broadcast
#pragma unroll
  for (int t4 = 0; t4 < 4; ++t4)
#pragma unroll
    for (int q = 0; q < 4; ++q)
      hT[(size_t)(n0 + l4 * 4 + q) * HH + J[t4]] = h[t4][q];
}

// ---------------------------------------------------------------------------
// hx_out[n,t,:] = hT[n,:]  (f32, overwrites the hs scratch region after gemm3)
__global__ void bcast_hT(const float* __restrict__ hT, float* __restrict__ dst) {
  const float4* s = (const float4*)hT;
  float4* d = (float4*)dst;
  const int total = NB * TT * HH / 4;
  const int stride = gridDim.x * blockDim.x;
  for (int c = blockIdx.x * blockDim.x + threadIdx.x; c < total; c += stride) {
    int n = c >> 15;
    int j4 = c & 127;
    d[c] = s[(n << 7) | j4];
  }
}

// ---------------------------------------------------------------------------
extern "C" void kernel_launch(void* const* d_in, const int* in_sizes, int n_in,
                              void* d_out, int out_size, void* d_ws, size_t ws_size,
                              hipStream_t stream) {
  const float* x    = (const float*)d_in[0];
  const float* hx   = (const float*)d_in[1];
  const float* Wih  = (const float*)d_in[2];
  const float* Whh  = (const float*)d_in[3];
  const float* bih  = (const float*)d_in[4];
  const float* bhh  = (const float*)d_in[5];
  const float* Wout = (const float*)d_in[6];
  const float* bout = (const float*)d_in[7];
  const unsigned char* isinit = (const unsigned char*)d_in[8];

  char* ws = (char*)d_ws;
  ushort_t* xi    = (ushort_t*)(ws);
  ushort_t* wihb  = (ushort_t*)(ws + 201326592);
  ushort_t* whhp  = (ushort_t*)(ws + 202899456);
  ushort_t* woutb = (ushort_t*)(ws + 204472320);
  unsigned char* mask8 = (unsigned char*)(ws + 204996608);
  float*    hTbuf = (float*)(ws + 205062144);

  float* out1 = (float*)d_out;                       // output [N,T,H] f32
  float* out2 = out1 + (size_t)NB * TT * HH;         // hx_out [N,T,H] f32
  ushort_t* hsb = (ushort_t*)out2;  // hs bf16 scratch until bcast overwrites

  mask_detect_kernel<<<1, 1024, 0, stream>>>(isinit, mask8);
  cvt_f2bf<<<768, 256, 0, stream>>>(Wih, wihb, GG * II / 4);
  cvt_f2bf<<<256, 256, 0, stream>>>(Wout, woutb, HH * HH / 4);
  pack_whh<<<384, 256, 0, stream>>>(Whh, whhp);

  dim3 g1(512, 12);  // M/128 x 3H/128
  gemm_bt<1, 0><<<g1, 256, 0, stream>>>((const void*)x, wihb, bih, (void*)xi, GG);

  gru_rec<<<16, 512, 114688, stream>>>(xi, whhp, hx, bhh, mask8, hsb, hTbuf);

  dim3 g3(512, 4);   // M/128 x H/128
  gemm_bt<0, 1><<<g3, 256, 0, stream>>>((const void*)hsb, woutb, bout, (void*)out1, HH);

  bcast_hT<<<2048, 256, 0, stream>>>(hTbuf, out2);
}

// Round 7
// 8488.442 us; speedup vs baseline: 1.4360x; 1.4099x over previous
//
#include <hip/hip_runtime.h>

// Problem constants
#define NB 256   // batch
#define TT 256   // time steps
#define II 512   // input dim
#define HH 512   // hidden dim
#define GG 1536  // 3*H gates

typedef unsigned short ushort_t;
typedef unsigned int uint_t;
typedef __attribute__((ext_vector_type(8))) short short8;   // 8 x bf16 (4 VGPRs)
typedef __attribute__((ext_vector_type(4))) float f32x4;    // MFMA accumulator

typedef __attribute__((address_space(3))) void lds_void;
typedef const __attribute__((address_space(1))) void glb_void;

__device__ __forceinline__ ushort_t f2bf(float f) {
  union { float f; unsigned int u; } x; x.f = f;
  unsigned int r = x.u + 0x7FFFu + ((x.u >> 16) & 1u);  // RNE
  return (ushort_t)(r >> 16);
}
__device__ __forceinline__ float bf2f(ushort_t b) {
  union { unsigned int u; float f; } x; x.u = ((unsigned int)b) << 16;
  return x.f;
}
__device__ __forceinline__ float sigmoidf_(float x) {
  return __fdividef(1.0f, 1.0f + __expf(-x));
}
__device__ __forceinline__ float tanhf_(float x) {
  float t = __expf(2.0f * x);
  return 1.0f - __fdividef(2.0f, t + 1.0f);
}
__device__ __forceinline__ short8 pack8(float4 a, float4 b) {
  short8 r;
  r[0] = (short)f2bf(a.x); r[1] = (short)f2bf(a.y);
  r[2] = (short)f2bf(a.z); r[3] = (short)f2bf(a.w);
  r[4] = (short)f2bf(b.x); r[5] = (short)f2bf(b.y);
  r[6] = (short)f2bf(b.z); r[7] = (short)f2bf(b.w);
  return r;
}

// ---------------------------------------------------------------------------
// is_init canonicalization -> uint8 mask (handles u8/i32/f32/i64 storage).
__global__ void mask_detect_kernel(const unsigned char* __restrict__ src,
                                   unsigned char* __restrict__ mask8) {
  __shared__ int fByte, fOdd;
  const int tid = threadIdx.x;
  if (tid == 0) { fByte = 0; fOdd = 0; }
  __syncthreads();
  const uint_t* w = (const uint_t*)src;
  int ab = 0, ao = 0;
  for (int i = tid; i < NB * TT; i += blockDim.x) {
    if ((i & 3) == 1 && src[i]) ab = 1;
    if (i < 16384 && (i & 1) == 1 && w[i]) ao = 1;
  }
  if (ab) fByte = 1;
  if (ao) fOdd = 1;
  __syncthreads();
  const int isByte = fByte, isW32 = fOdd;
  for (int i = tid; i < NB * TT; i += blockDim.x) {
    unsigned char m;
    if (isByte)      m = src[i] ? 1 : 0;
    else if (isW32)  m = w[i] ? 1 : 0;
    else             m = w[2 * i] ? 1 : 0;
    mask8[i] = m;
  }
}

// ---------------------------------------------------------------------------
__global__ void cvt_f2bf(const float* __restrict__ src, ushort_t* __restrict__ dst,
                         int n4) {
  int stride = gridDim.x * blockDim.x;
  for (int i = blockIdx.x * blockDim.x + threadIdx.x; i < n4; i += stride) {
    const float4 v = reinterpret_cast<const float4*>(src)[i];
    ushort4 o;
    o.x = f2bf(v.x); o.y = f2bf(v.y); o.z = f2bf(v.z); o.w = f2bf(v.w);
    reinterpret_cast<ushort4*>(dst)[i] = o;
  }
}

// ---------------------------------------------------------------------------
// Pack W_hh [1536][512] f32 into MFMA-B-fragment order (bf16):
// Wpk[((tile*16+kk)*64 + lane)*8 + e] = W[tile*16 + (lane&15)][kk*32 + (lane>>4)*8 + e]
__global__ void pack_whh(const float* __restrict__ W, ushort_t* __restrict__ out) {
  int idx = blockIdx.x * blockDim.x + threadIdx.x;  // 96*16*64 = 98304
  if (idx >= 96 * 16 * 64) return;
  int l = idx & 63;
  int tk = idx >> 6;
  int tile = tk >> 4, kk = tk & 15;
  int row = tile * 16 + (l & 15);
  int k = kk * 32 + (l >> 4) * 8;
  const float* s = W + (size_t)row * HH + k;
  short8 v;
#pragma unroll
  for (int e = 0; e < 8; ++e) v[e] = (short)f2bf(s[e]);
  *reinterpret_cast<short8*>(out + (size_t)idx * 8) = v;
}

// ---------------------------------------------------------------------------
// GEMM: C[m][c] = sum_k A[m][k]*B[c][k] + bias[c].  (unchanged)
template <int AF32, int CF32>
__global__ __launch_bounds__(256) void gemm_bt(
    const void* __restrict__ Av, const ushort_t* __restrict__ B,
    const float* __restrict__ bias, void* __restrict__ Cv, int NC) {
  __shared__ ushort_t As[128 * 32];
  __shared__ ushort_t Bs[128 * 32];
  const int tid = threadIdx.x;
  const int lane = tid & 63;
  const int w = tid >> 6;
  const int wr = w >> 1, wc = w & 1;
  const int c15 = lane & 15, l4 = lane >> 4;
  const int mbase = blockIdx.x * 128;
  const int nbase = blockIdx.y * 128;

  const int rs = tid >> 2;
  const int kb = (tid & 3) * 8;

  f32x4 acc[4][4] = {};

  const float4* Bg = reinterpret_cast<const float4*>(B);
  auto bIdx = [&](int c, int kt) {
    return ((size_t)(nbase + rs + 64 * c) * 512 + kt * 32 + kb) >> 3;
  };
  float4 rb0 = Bg[bIdx(0, 0)], rb1 = Bg[bIdx(1, 0)];

  const float4* Agf = reinterpret_cast<const float4*>(Av);
  auto aEl = [&](int c, int kt) {
    return (size_t)(mbase + rs + 64 * c) * 512 + kt * 32 + kb;
  };
  float4 a0a, a0b, a1a, a1b;
  float4 h0, h1;
  if constexpr (AF32) {
    a0a = Agf[aEl(0, 0) >> 2]; a0b = Agf[(aEl(0, 0) >> 2) + 1];
    a1a = Agf[aEl(1, 0) >> 2]; a1b = Agf[(aEl(1, 0) >> 2) + 1];
  } else {
    h0 = Agf[aEl(0, 0) >> 3];
    h1 = Agf[aEl(1, 0) >> 3];
  }

  for (int kt = 0; kt < 16; ++kt) {
    __syncthreads();
    if constexpr (AF32) {
      *reinterpret_cast<short8*>(&As[(size_t)tid * 8]) = pack8(a0a, a0b);
      *reinterpret_cast<short8*>(&As[(size_t)(tid + 256) * 8]) = pack8(a1a, a1b);
    } else {
      reinterpret_cast<float4*>(As)[tid] = h0;
      reinterpret_cast<float4*>(As)[tid + 256] = h1;
    }
    reinterpret_cast<float4*>(Bs)[tid] = rb0;
    reinterpret_cast<float4*>(Bs)[tid + 256] = rb1;
    if (kt < 15) {
      if constexpr (AF32) {
        a0a = Agf[aEl(0, kt + 1) >> 2]; a0b = Agf[(aEl(0, kt + 1) >> 2) + 1];
        a1a = Agf[aEl(1, kt + 1) >> 2]; a1b = Agf[(aEl(1, kt + 1) >> 2) + 1];
      } else {
        h0 = Agf[aEl(0, kt + 1) >> 3];
        h1 = Agf[aEl(1, kt + 1) >> 3];
      }
      rb0 = Bg[bIdx(0, kt + 1)]; rb1 = Bg[bIdx(1, kt + 1)];
    }
    __syncthreads();
    short8 af[4], bq[4];
#pragma unroll
    for (int m = 0; m < 4; ++m)
      af[m] = *reinterpret_cast<const short8*>(&As[(wr * 64 + m * 16 + c15) * 32 + l4 * 8]);
#pragma unroll
    for (int n = 0; n < 4; ++n)
      bq[n] = *reinterpret_cast<const short8*>(&Bs[(wc * 64 + n * 16 + c15) * 32 + l4 * 8]);
#pragma unroll
    for (int m = 0; m < 4; ++m)
#pragma unroll
      for (int n = 0; n < 4; ++n)
        acc[m][n] = __builtin_amdgcn_mfma_f32_16x16x32_bf16(af[m], bq[n], acc[m][n], 0, 0, 0);
  }

#pragma unroll
  for (int n = 0; n < 4; ++n) {
    const int col = nbase + wc * 64 + n * 16 + c15;
    const float bv = bias[col];
#pragma unroll
    for (int m = 0; m < 4; ++m) {
      const int row = mbase + wr * 64 + m * 16 + l4 * 4;
#pragma unroll
      for (int q = 0; q < 4; ++q) {
        const float v = acc[m][n][q] + bv;
        if constexpr (CF32)
          reinterpret_cast<float*>(Cv)[(size_t)(row + q) * NC + col] = v;
        else
          reinterpret_cast<ushort_t*>(Cv)[(size_t)(row + q) * NC + col] = f2bf(v);
      }
    }
  }
}

// ---------------------------------------------------------------------------
// GRU recurrence v5: W-in-registers + inter-block h exchange.
// 128 blocks x 256 threads (4 waves, 1 wave/SIMD -> 512-VGPR cap).
// Block (a = bid&7, b = bid>>3): samples [b*16,+16), hidden cols [a*64,+64)
// x 3 gates. Wave w owns j-tile [a*64+w*16,+16): 3 MFMA tiles x 16 kk, with
// the W fragments held in 192 VGPRs (loaded once -> NO per-step W traffic).
// Per step: 8-block cluster exchanges h slices through a global buffer with
// per-block flag atomics (agent scope, double-buffered slots).
__global__ __launch_bounds__(256, 1) void gru_rec(
    const ushort_t* __restrict__ xi, const ushort_t* __restrict__ Wpk,
    const float* __restrict__ hx, const float* __restrict__ bhh,
    const unsigned char* __restrict__ mask8,
    ushort_t* __restrict__ hs, float* __restrict__ hT,
    char* __restrict__ xch, uint_t* __restrict__ flags) {
  __shared__ ushort_t hA[16 * 512];    // h(t) bf16, XOR-swizzled image (16 KB)
  __shared__ ushort_t xiL[16 * 192];   // xi(t) slice for this block (6 KB)

  const int tid = threadIdx.x;
  const int lane = tid & 63;
  const int w = tid >> 6;              // wave 0..3 -> j-subtile
  const int c15 = lane & 15, l4 = lane >> 4;
  const int bid = blockIdx.x;
  const int a = bid & 7;               // hidden-col group
  const int b = bid >> 3;              // sample group
  const int n0 = b * 16;

  const int jl = w * 16 + c15;         // [0,64) local hidden col
  const int jfull = a * 64 + jl;       // [0,512)
  const float br = bhh[jfull], bz = bhh[512 + jfull], bn = bhh[1024 + jfull];

  // ---- W slice into registers: 3 gates x 16 kk x 16B = 192 VGPRs
  short8 wreg[3][16];
#pragma unroll
  for (int g = 0; g < 3; ++g)
#pragma unroll
    for (int kk = 0; kk < 16; ++kk)
      wreg[g][kk] = *(const short8*)(
          Wpk + (((size_t)(g * 32 + a * 4 + w) * 16 + kk) * 64 + lane) * 8);

  // ---- xi DMA geometry: 384 chunks = [16 s][3 g][8 p]; thread: c=tid, c=tid+256
  size_t xg0, xg1 = 0;
  {
    int c = tid, s = c / 24, r = c % 24, g = r >> 3, p = r & 7;
    xg0 = ((size_t)(n0 + s) * TT) * GG + g * 512 + a * 64 + p * 8;
    if (tid < 128) {
      c = tid + 256; s = c / 24; r = c % 24; g = r >> 3; p = r & 7;
      xg1 = ((size_t)(n0 + s) * TT) * GG + g * 512 + a * 64 + p * 8;
    }
  }
  const int xl0 = tid * 8, xl1 = (tid + 256) * 8;

  // ---- exchange addressing
  char* slot0 = xch + (size_t)(b * 2) * 16384;
  char* slot1 = xch + (size_t)(b * 2 + 1) * 16384;

  // ---- prologue: h(0) = mask0 ? 0 : hx[:,0,:]; publish to slot0
  float h[4];
#pragma unroll
  for (int q = 0; q < 4; ++q) {
    const int s = l4 * 4 + q;
    const bool mk0 = mask8[(size_t)(n0 + s) * TT] != 0;
    const float v = mk0 ? 0.0f : hx[((size_t)(n0 + s) * TT) * HH + jfull];
    h[q] = v;
    *(ushort_t*)(slot0 + s * 1024 + jfull * 2) = f2bf(v);
  }
  __threadfence();
  __syncthreads();
  if (tid == 0)
    __hip_atomic_store(&flags[bid * 16], 1u, __ATOMIC_RELEASE,
                       __HIP_MEMORY_SCOPE_AGENT);

  for (int t = 0; t < TT; ++t) {
    // ---- spin: cluster peers published h(t)
    if (tid < 8) {
      const uint_t tgt = (uint_t)(t + 1);
      while (__hip_atomic_load(&flags[(b * 8 + tid) * 16], __ATOMIC_RELAXED,
                               __HIP_MEMORY_SCOPE_AGENT) < tgt) {}
    }
    __syncthreads();
    __threadfence();   // acquire: invalidate local L2 before exchange reads

    // ---- issue xi(t) DMA (consumed in phase C, latency hidden)
    __builtin_amdgcn_global_load_lds((glb_void*)(xi + xg0 + (size_t)t * GG),
                                     (lds_void*)(xiL + xl0), 16, 0, 0);
    if (tid < 128)
      __builtin_amdgcn_global_load_lds((glb_void*)(xi + xg1 + (size_t)t * GG),
                                       (lds_void*)(xiL + xl1), 16, 0, 0);

    // ---- gather h(t): 16 KB from exchange slot -> swizzled hA image
    const char* src = (t & 1) ? slot1 : slot0;
#pragma unroll
    for (int k = 0; k < 4; ++k) {
      const int c = tid + k * 256;           // [0,1024) 16B chunks
      const int s = c >> 6, cb = (c & 63) * 16;
      const float4 v = *(const float4*)(src + s * 1024 + cb);
      *(float4*)((char*)hA + s * 1024 + (cb ^ ((s & 7) << 4))) = v;
    }
    __syncthreads();   // hA + xiL ready (barrier drains DMA + LDS writes)

    // ---- MFMA: A-frags from hA, B-frags from wreg (registers)
    short8 af[16];
#pragma unroll
    for (int kk = 0; kk < 16; ++kk)
      af[kk] = *(const short8*)(
          (char*)hA + c15 * 1024 + ((kk * 64 + l4 * 16) ^ ((c15 & 7) << 4)));

    f32x4 a0 = {0.f, 0.f, 0.f, 0.f}, a1 = a0, a2 = a0;
#pragma unroll
    for (int kk = 0; kk < 16; ++kk) {
      a0 = __builtin_amdgcn_mfma_f32_16x16x32_bf16(af[kk], wreg[0][kk], a0, 0, 0, 0);
      a1 = __builtin_amdgcn_mfma_f32_16x16x32_bf16(af[kk], wreg[1][kk], a1, 0, 0, 0);
      a2 = __builtin_amdgcn_mfma_f32_16x16x32_bf16(af[kk], wreg[2][kk], a2, 0, 0, 0);
    }

    // ---- next-step mask bytes
    const bool domask = (t + 1 < TT);
    const int tn = domask ? (t + 1) : t;
    unsigned char mkv[4];
#pragma unroll
    for (int q = 0; q < 4; ++q)
      mkv[q] = mask8[(size_t)(n0 + l4 * 4 + q) * TT + tn];

    // ---- gates + h update + publish h(t+1)
    char* dst = ((t + 1) & 1) ? slot1 : slot0;
#pragma unroll
    for (int q = 0; q < 4; ++q) {
      const int s = l4 * 4 + q;
      const float xr = bf2f(xiL[s * 192 + jl]);
      const float xz = bf2f(xiL[s * 192 + 64 + jl]);
      const float xn = bf2f(xiL[s * 192 + 128 + jl]);
      const float rr = sigmoidf_(xr + a0[q] + br);
      const float zz = sigmoidf_(xz + a1[q] + bz);
      const float nn = tanhf_(xn + rr * (a2[q] + bn));
      const float hnew = (1.0f - zz) * nn + zz * h[q];
      hs[((size_t)(n0 + s) * TT + t) * HH + jfull] = f2bf(hnew);
      const float hp = (domask && mkv[q]) ? 0.0f : hnew;
      h[q] = hp;
      if (domask) *(ushort_t*)(dst + s * 1024 + jfull * 2) = f2bf(hp);
    }

    if (domask) {
      __threadfence();   // release: own stores -> coherent point
      __syncthreads();
      if (tid == 0)
        __hip_atomic_store(&flags[bid * 16], (uint_t)(t + 2), __ATOMIC_RELEASE,
                           __HIP_MEMORY_SCOPE_AGENT);
    }
  }

  // ---- epilogue: final h (unmasked) -> hT f32
#pragma unroll
  for (int q = 0; q < 4; ++q)
    hT[(size_t)(n0 + l4 * 4 + q) * HH + jfull] = h[q];
}

// ---------------------------------------------------------------------------
// hx_out[n,t,:] = hT[n,:]  (f32, overwrites the hs scratch region after gemm3)
__global__ void bcast_hT(const float* __restrict__ hT, float* __restrict__ dst) {
  const float4* s = (const float4*)hT;
  float4* d = (float4*)dst;
  const int total = NB * TT * HH / 4;
  const int stride = gridDim.x * blockDim.x;
  for (int c = blockIdx.x * blockDim.x + threadIdx.x; c < total; c += stride) {
    int n = c >> 15;
    int j4 = c & 127;
    d[c] = s[(n << 7) | j4];
  }
}

// ---------------------------------------------------------------------------
extern "C" void kernel_launch(void* const* d_in, const int* in_sizes, int n_in,
                              void* d_out, int out_size, void* d_ws, size_t ws_size,
                              hipStream_t stream) {
  const float* x    = (const float*)d_in[0];
  const float* hx   = (const float*)d_in[1];
  const float* Wih  = (const float*)d_in[2];
  const float* Whh  = (const float*)d_in[3];
  const float* bih  = (const float*)d_in[4];
  const float* bhh  = (const float*)d_in[5];
  const float* Wout = (const float*)d_in[6];
  const float* bout = (const float*)d_in[7];
  const unsigned char* isinit = (const unsigned char*)d_in[8];

  // Workspace layout (~206.2 MiB):
  //   xi    bf16 [65536][1536] @ 0
  //   wihb  bf16               @ 201,326,592
  //   whhp  packed bf16        @ 202,899,456
  //   woutb bf16               @ 204,472,320
  //   mask8 u8                 @ 204,996,608
  //   hTbuf f32 [256][512]     @ 205,062,144
  //   flags u32[128*16]        @ 205,586,432  (8 KB, zeroed per launch)
  //   xch   [16][2][16][512]bf @ 205,594,624  (512 KB)
  char* ws = (char*)d_ws;
  ushort_t* xi    = (ushort_t*)(ws);
  ushort_t* wihb  = (ushort_t*)(ws + 201326592);
  ushort_t* whhp  = (ushort_t*)(ws + 202899456);
  ushort_t* woutb = (ushort_t*)(ws + 204472320);
  unsigned char* mask8 = (unsigned char*)(ws + 204996608);
  float*    hTbuf = (float*)(ws + 205062144);
  uint_t*   flags = (uint_t*)(ws + 205586432);
  char*     xch   = (char*)(ws + 205594624);

  float* out1 = (float*)d_out;                       // output [N,T,H] f32
  float* out2 = out1 + (size_t)NB * TT * HH;         // hx_out [N,T,H] f32
  ushort_t* hsb = (ushort_t*)out2;  // hs bf16 scratch until bcast overwrites

  hipMemsetAsync(flags, 0, 128 * 16 * sizeof(uint_t), stream);
  mask_detect_kernel<<<1, 1024, 0, stream>>>(isinit, mask8);
  cvt_f2bf<<<768, 256, 0, stream>>>(Wih, wihb, GG * II / 4);
  cvt_f2bf<<<256, 256, 0, stream>>>(Wout, woutb, HH * HH / 4);
  pack_whh<<<384, 256, 0, stream>>>(Whh, whhp);

  dim3 g1(512, 12);  // M/128 x 3H/128
  gemm_bt<1, 0><<<g1, 256, 0, stream>>>((const void*)x, wihb, bih, (void*)xi, GG);

  gru_rec<<<128, 256, 0, stream>>>(xi, whhp, hx, bhh, mask8, hsb, hTbuf,
                                   xch, flags);

  dim3 g3(512, 4);   // M/128 x H/128
  gemm_bt<0, 1><<<g3, 256, 0, stream>>>((const void*)hsb, woutb, bout, (void*)out1, HH);

  bcast_hT<<<2048, 256, 0, stream>>>(hTbuf, out2);
}

// Round 8
// 2506.554 us; speedup vs baseline: 4.8631x; 3.3865x over previous
//
#include <hip/hip_runtime.h>

// Problem constants
#define NB 256   // batch
#define TT 256   // time steps
#define II 512   // input dim
#define HH 512   // hidden dim
#define GG 1536  // 3*H gates

typedef unsigned short ushort_t;
typedef unsigned int uint_t;
typedef unsigned long long ull_t;
typedef __attribute__((ext_vector_type(8))) short short8;   // 8 x bf16 (4 VGPRs)
typedef __attribute__((ext_vector_type(4))) float f32x4;    // MFMA accumulator

typedef __attribute__((address_space(3))) void lds_void;
typedef const __attribute__((address_space(1))) void glb_void;

__device__ __forceinline__ ushort_t f2bf(float f) {
  union { float f; unsigned int u; } x; x.f = f;
  unsigned int r = x.u + 0x7FFFu + ((x.u >> 16) & 1u);  // RNE
  return (ushort_t)(r >> 16);
}
__device__ __forceinline__ float bf2f(ushort_t b) {
  union { unsigned int u; float f; } x; x.u = ((unsigned int)b) << 16;
  return x.f;
}
__device__ __forceinline__ float sigmoidf_(float x) {
  return __fdividef(1.0f, 1.0f + __expf(-x));
}
__device__ __forceinline__ float tanhf_(float x) {
  float t = __expf(2.0f * x);
  return 1.0f - __fdividef(2.0f, t + 1.0f);
}
__device__ __forceinline__ short8 pack8(float4 a, float4 b) {
  short8 r;
  r[0] = (short)f2bf(a.x); r[1] = (short)f2bf(a.y);
  r[2] = (short)f2bf(a.z); r[3] = (short)f2bf(a.w);
  r[4] = (short)f2bf(b.x); r[5] = (short)f2bf(b.y);
  r[6] = (short)f2bf(b.z); r[7] = (short)f2bf(b.w);
  return r;
}

// ---------------------------------------------------------------------------
// is_init canonicalization -> uint8 mask (handles u8/i32/f32/i64 storage).
__global__ void mask_detect_kernel(const unsigned char* __restrict__ src,
                                   unsigned char* __restrict__ mask8) {
  __shared__ int fByte, fOdd;
  const int tid = threadIdx.x;
  if (tid == 0) { fByte = 0; fOdd = 0; }
  __syncthreads();
  const uint_t* w = (const uint_t*)src;
  int ab = 0, ao = 0;
  for (int i = tid; i < NB * TT; i += blockDim.x) {
    if ((i & 3) == 1 && src[i]) ab = 1;
    if (i < 16384 && (i & 1) == 1 && w[i]) ao = 1;
  }
  if (ab) fByte = 1;
  if (ao) fOdd = 1;
  __syncthreads();
  const int isByte = fByte, isW32 = fOdd;
  for (int i = tid; i < NB * TT; i += blockDim.x) {
    unsigned char m;
    if (isByte)      m = src[i] ? 1 : 0;
    else if (isW32)  m = w[i] ? 1 : 0;
    else             m = w[2 * i] ? 1 : 0;
    mask8[i] = m;
  }
}

// ---------------------------------------------------------------------------
__global__ void cvt_f2bf(const float* __restrict__ src, ushort_t* __restrict__ dst,
                         int n4) {
  int stride = gridDim.x * blockDim.x;
  for (int i = blockIdx.x * blockDim.x + threadIdx.x; i < n4; i += stride) {
    const float4 v = reinterpret_cast<const float4*>(src)[i];
    ushort4 o;
    o.x = f2bf(v.x); o.y = f2bf(v.y); o.z = f2bf(v.z); o.w = f2bf(v.w);
    reinterpret_cast<ushort4*>(dst)[i] = o;
  }
}

// ---------------------------------------------------------------------------
// Pack W_hh [1536][512] f32 into MFMA-B-fragment order (bf16):
// Wpk[((tile*16+kk)*64 + lane)*8 + e] = W[tile*16 + (lane&15)][kk*32 + (lane>>4)*8 + e]
__global__ void pack_whh(const float* __restrict__ W, ushort_t* __restrict__ out) {
  int idx = blockIdx.x * blockDim.x + threadIdx.x;  // 96*16*64 = 98304
  if (idx >= 96 * 16 * 64) return;
  int l = idx & 63;
  int tk = idx >> 6;
  int tile = tk >> 4, kk = tk & 15;
  int row = tile * 16 + (l & 15);
  int k = kk * 32 + (l >> 4) * 8;
  const float* s = W + (size_t)row * HH + k;
  short8 v;
#pragma unroll
  for (int e = 0; e < 8; ++e) v[e] = (short)f2bf(s[e]);
  *reinterpret_cast<short8*>(out + (size_t)idx * 8) = v;
}

// ---------------------------------------------------------------------------
// GEMM: C[m][c] = sum_k A[m][k]*B[c][k] + bias[c].  (unchanged)
template <int AF32, int CF32>
__global__ __launch_bounds__(256) void gemm_bt(
    const void* __restrict__ Av, const ushort_t* __restrict__ B,
    const float* __restrict__ bias, void* __restrict__ Cv, int NC) {
  __shared__ ushort_t As[128 * 32];
  __shared__ ushort_t Bs[128 * 32];
  const int tid = threadIdx.x;
  const int lane = tid & 63;
  const int w = tid >> 6;
  const int wr = w >> 1, wc = w & 1;
  const int c15 = lane & 15, l4 = lane >> 4;
  const int mbase = blockIdx.x * 128;
  const int nbase = blockIdx.y * 128;

  const int rs = tid >> 2;
  const int kb = (tid & 3) * 8;

  f32x4 acc[4][4] = {};

  const float4* Bg = reinterpret_cast<const float4*>(B);
  auto bIdx = [&](int c, int kt) {
    return ((size_t)(nbase + rs + 64 * c) * 512 + kt * 32 + kb) >> 3;
  };
  float4 rb0 = Bg[bIdx(0, 0)], rb1 = Bg[bIdx(1, 0)];

  const float4* Agf = reinterpret_cast<const float4*>(Av);
  auto aEl = [&](int c, int kt) {
    return (size_t)(mbase + rs + 64 * c) * 512 + kt * 32 + kb;
  };
  float4 a0a, a0b, a1a, a1b;
  float4 h0, h1;
  if constexpr (AF32) {
    a0a = Agf[aEl(0, 0) >> 2]; a0b = Agf[(aEl(0, 0) >> 2) + 1];
    a1a = Agf[aEl(1, 0) >> 2]; a1b = Agf[(aEl(1, 0) >> 2) + 1];
  } else {
    h0 = Agf[aEl(0, 0) >> 3];
    h1 = Agf[aEl(1, 0) >> 3];
  }

  for (int kt = 0; kt < 16; ++kt) {
    __syncthreads();
    if constexpr (AF32) {
      *reinterpret_cast<short8*>(&As[(size_t)tid * 8]) = pack8(a0a, a0b);
      *reinterpret_cast<short8*>(&As[(size_t)(tid + 256) * 8]) = pack8(a1a, a1b);
    } else {
      reinterpret_cast<float4*>(As)[tid] = h0;
      reinterpret_cast<float4*>(As)[tid + 256] = h1;
    }
    reinterpret_cast<float4*>(Bs)[tid] = rb0;
    reinterpret_cast<float4*>(Bs)[tid + 256] = rb1;
    if (kt < 15) {
      if constexpr (AF32) {
        a0a = Agf[aEl(0, kt + 1) >> 2]; a0b = Agf[(aEl(0, kt + 1) >> 2) + 1];
        a1a = Agf[aEl(1, kt + 1) >> 2]; a1b = Agf[(aEl(1, kt + 1) >> 2) + 1];
      } else {
        h0 = Agf[aEl(0, kt + 1) >> 3];
        h1 = Agf[aEl(1, kt + 1) >> 3];
      }
      rb0 = Bg[bIdx(0, kt + 1)]; rb1 = Bg[bIdx(1, kt + 1)];
    }
    __syncthreads();
    short8 af[4], bq[4];
#pragma unroll
    for (int m = 0; m < 4; ++m)
      af[m] = *reinterpret_cast<const short8*>(&As[(wr * 64 + m * 16 + c15) * 32 + l4 * 8]);
#pragma unroll
    for (int n = 0; n < 4; ++n)
      bq[n] = *reinterpret_cast<const short8*>(&Bs[(wc * 64 + n * 16 + c15) * 32 + l4 * 8]);
#pragma unroll
    for (int m = 0; m < 4; ++m)
#pragma unroll
      for (int n = 0; n < 4; ++n)
        acc[m][n] = __builtin_amdgcn_mfma_f32_16x16x32_bf16(af[m], bq[n], acc[m][n], 0, 0, 0);
  }

#pragma unroll
  for (int n = 0; n < 4; ++n) {
    const int col = nbase + wc * 64 + n * 16 + c15;
    const float bv = bias[col];
#pragma unroll
    for (int m = 0; m < 4; ++m) {
      const int row = mbase + wr * 64 + m * 16 + l4 * 4;
#pragma unroll
      for (int q = 0; q < 4; ++q) {
        const float v = acc[m][n][q] + bv;
        if constexpr (CF32)
          reinterpret_cast<float*>(Cv)[(size_t)(row + q) * NC + col] = v;
        else
          reinterpret_cast<ushort_t*>(Cv)[(size_t)(row + q) * NC + col] = f2bf(v);
      }
    }
  }
}

// ---------------------------------------------------------------------------
// GRU recurrence v6: fence-free L3 exchange protocol.
// 128 blocks x 256 threads (4 waves). Block (a=bid&7, b=bid>>3): samples
// [b*16,+16), hidden cols [a*64,+64) x 3 gates; wave w owns col-tile
// [a*64+w*16,+16) x 3 gates.
// Coherence: ALL cross-block data moves via sc1 (agent-scope relaxed atomic)
// loads/stores that read/write L3 directly -- NO __threadfence, NO L2
// invalidates, so W_hh stays warm in per-XCD L2 across all 256 steps.
// hs written nontemporal to keep L2 clean.
__global__ __launch_bounds__(256, 1) void gru_rec(
    const ushort_t* __restrict__ xi, const ushort_t* __restrict__ Wpk,
    const float* __restrict__ hx, const float* __restrict__ bhh,
    const unsigned char* __restrict__ mask8,
    ushort_t* __restrict__ hs, float* __restrict__ hT,
    char* __restrict__ xch, uint_t* __restrict__ flags) {
  __shared__ ushort_t hA[16 * 512];      // h(t) bf16, XOR-swizzled (16 KB)
  __shared__ ushort_t xiL[2][16 * 192];  // xi(t) slice, double-buffered (12 KB)

  const int tid = threadIdx.x;
  const int lane = tid & 63;
  const int w = tid >> 6;              // wave 0..3 -> col-tile
  const int c15 = lane & 15, l4 = lane >> 4;
  const int bid = blockIdx.x;
  const int a = bid & 7;               // hidden-col group
  const int b = bid >> 3;              // sample group
  const int n0 = b * 16;

  const int jl = w * 16 + c15;         // [0,64) local hidden col
  const int jfull = a * 64 + jl;       // [0,512)
  const float br = bhh[jfull], bz = bhh[512 + jfull], bn = bhh[1024 + jfull];

  // W fragment bases (ushort units) for the wave's 3 gate-tiles
  const int wb0 = ((0 * 32 + a * 4 + w) * 16) * 512 + lane * 8;
  const int wb1 = ((1 * 32 + a * 4 + w) * 16) * 512 + lane * 8;
  const int wb2 = ((2 * 32 + a * 4 + w) * 16) * 512 + lane * 8;

  // xi DMA geometry: 384 chunks = [16 s][3 g][8 p]; thread: c=tid, c=tid+256
  size_t xg0, xg1 = 0;
  {
    int c = tid, s = c / 24, r = c % 24, g = r >> 3, p = r & 7;
    xg0 = ((size_t)(n0 + s) * TT) * GG + g * 512 + a * 64 + p * 8;
    if (tid < 128) {
      c = tid + 256; s = c / 24; r = c % 24; g = r >> 3; p = r & 7;
      xg1 = ((size_t)(n0 + s) * TT) * GG + g * 512 + a * 64 + p * 8;
    }
  }
  const int xl0 = tid * 8, xl1 = (tid + 256) * 8;

  // exchange slots for this cluster (8 blocks sharing sample group b)
  char* slot0 = xch + (size_t)(b * 2) * 16384;
  char* slot1 = xch + (size_t)(b * 2 + 1) * 16384;

  // ---- prologue: h(0) = mask0 ? 0 : hx[:,0,:]; publish (sc1) to slot0
  float h[4];
#pragma unroll
  for (int q = 0; q < 4; ++q) {
    const int s = l4 * 4 + q;
    const bool mk0 = mask8[(size_t)(n0 + s) * TT] != 0;
    const float v = mk0 ? 0.0f : hx[((size_t)(n0 + s) * TT) * HH + jfull];
    h[q] = v;
    __hip_atomic_store((ushort_t*)(slot0 + s * 1024 + jfull * 2), f2bf(v),
                       __ATOMIC_RELAXED, __HIP_MEMORY_SCOPE_AGENT);
  }
  __syncthreads();   // drains vmcnt(0): all sc1 publishes at L3
  if (tid == 0)
    __hip_atomic_store(&flags[bid * 32], 1u, __ATOMIC_RELEASE,
                       __HIP_MEMORY_SCOPE_AGENT);

  for (int t = 0; t < TT; ++t) {
    // ---- A: issue xi(t) DMA into buffer t&1 (overlaps the spin)
    ushort_t* xb = xiL[t & 1];
    __builtin_amdgcn_global_load_lds((glb_void*)(xi + xg0 + (size_t)t * GG),
                                     (lds_void*)(xb + xl0), 16, 0, 0);
    if (tid < 128)
      __builtin_amdgcn_global_load_lds((glb_void*)(xi + xg1 + (size_t)t * GG),
                                       (lds_void*)(xb + xl1), 16, 0, 0);

    // ---- B: spin until cluster peers published h(t) (sc1 poll, no inv)
    if (tid < 8) {
      const uint_t tgt = (uint_t)(t + 1);
      while (__hip_atomic_load(&flags[(b * 8 + tid) * 32], __ATOMIC_RELAXED,
                               __HIP_MEMORY_SCOPE_AGENT) < tgt) {}
    }
    __syncthreads();

    // ---- D: gather h(t) 16KB from L3 (sc1) -> swizzled hA image
    const char* src = (t & 1) ? slot1 : slot0;
#pragma unroll
    for (int i = 0; i < 8; ++i) {
      const int c = tid * 8 + i;             // 8B chunk id [0,2048)
      const int s = c >> 7, cb = (c & 127) * 8;
      const ull_t v = __hip_atomic_load((const ull_t*)(src + s * 1024 + cb),
                                        __ATOMIC_RELAXED,
                                        __HIP_MEMORY_SCOPE_AGENT);
      *(ull_t*)((char*)hA + s * 1024 + (cb ^ ((s & 7) << 4))) = v;
    }

    // next-step mask bytes (L1/L2-hot: no invalidates anymore)
    const bool domask = (t + 1 < TT);
    const int tn = domask ? (t + 1) : t;
    unsigned char mkv[4];
#pragma unroll
    for (int q = 0; q < 4; ++q)
      mkv[q] = mask8[(size_t)(n0 + l4 * 4 + q) * TT + tn];

    __syncthreads();   // hA ready; also drains xi DMA

    // ---- F: MFMA. A-frags from hA (LDS), W streamed from warm L2.
    short8 af[16];
#pragma unroll
    for (int kk = 0; kk < 16; ++kk)
      af[kk] = *(const short8*)(
          (char*)hA + c15 * 1024 + ((kk * 64 + l4 * 16) ^ ((c15 & 7) << 4)));

    f32x4 a0 = {0.f, 0.f, 0.f, 0.f}, a1 = a0, a2 = a0;
#pragma unroll
    for (int kk = 0; kk < 16; ++kk) {
      const short8 w0 = *(const short8*)(Wpk + wb0 + kk * 512);
      const short8 w1 = *(const short8*)(Wpk + wb1 + kk * 512);
      const short8 w2 = *(const short8*)(Wpk + wb2 + kk * 512);
      a0 = __builtin_amdgcn_mfma_f32_16x16x32_bf16(af[kk], w0, a0, 0, 0, 0);
      a1 = __builtin_amdgcn_mfma_f32_16x16x32_bf16(af[kk], w1, a1, 0, 0, 0);
      a2 = __builtin_amdgcn_mfma_f32_16x16x32_bf16(af[kk], w2, a2, 0, 0, 0);
    }

    // ---- G/H: gates + h update; hs nontemporal; publish h(t+1) via sc1
    char* dst = ((t + 1) & 1) ? slot1 : slot0;
#pragma unroll
    for (int q = 0; q < 4; ++q) {
      const int s = l4 * 4 + q;
      const float xr = bf2f(xb[s * 192 + jl]);
      const float xz = bf2f(xb[s * 192 + 64 + jl]);
      const float xn = bf2f(xb[s * 192 + 128 + jl]);
      const float rr = sigmoidf_(xr + a0[q] + br);
      const float zz = sigmoidf_(xz + a1[q] + bz);
      const float nn = tanhf_(xn + rr * (a2[q] + bn));
      const float hnew = (1.0f - zz) * nn + zz * h[q];
      __builtin_nontemporal_store(
          f2bf(hnew), &hs[((size_t)(n0 + s) * TT + t) * HH + jfull]);
      const float hp = (domask && mkv[q]) ? 0.0f : hnew;
      h[q] = hp;
      if (domask)
        __hip_atomic_store((ushort_t*)(dst + s * 1024 + jfull * 2), f2bf(hp),
                           __ATOMIC_RELAXED, __HIP_MEMORY_SCOPE_AGENT);
    }

    if (domask) {
      __syncthreads();   // drains vmcnt: all 256 threads' publishes at L3
      if (tid == 0)
        __hip_atomic_store(&flags[bid * 32], (uint_t)(t + 2), __ATOMIC_RELEASE,
                           __HIP_MEMORY_SCOPE_AGENT);
    }
  }

  // ---- epilogue: final h (unmasked) -> hT f32
#pragma unroll
  for (int q = 0; q < 4; ++q)
    hT[(size_t)(n0 + l4 * 4 + q) * HH + jfull] = h[q];
}

// ---------------------------------------------------------------------------
// hx_out[n,t,:] = hT[n,:]  (f32, overwrites the hs scratch region after gemm3)
__global__ void bcast_hT(const float* __restrict__ hT, float* __restrict__ dst) {
  const float4* s = (const float4*)hT;
  float4* d = (float4*)dst;
  const int total = NB * TT * HH / 4;
  const int stride = gridDim.x * blockDim.x;
  for (int c = blockIdx.x * blockDim.x + threadIdx.x; c < total; c += stride) {
    int n = c >> 15;
    int j4 = c & 127;
    d[c] = s[(n << 7) | j4];
  }
}

// ---------------------------------------------------------------------------
extern "C" void kernel_launch(void* const* d_in, const int* in_sizes, int n_in,
                              void* d_out, int out_size, void* d_ws, size_t ws_size,
                              hipStream_t stream) {
  const float* x    = (const float*)d_in[0];
  const float* hx   = (const float*)d_in[1];
  const float* Wih  = (const float*)d_in[2];
  const float* Whh  = (const float*)d_in[3];
  const float* bih  = (const float*)d_in[4];
  const float* bhh  = (const float*)d_in[5];
  const float* Wout = (const float*)d_in[6];
  const float* bout = (const float*)d_in[7];
  const unsigned char* isinit = (const unsigned char*)d_in[8];

  // Workspace layout (~196.6 MiB):
  //   xi    bf16 [65536][1536] @ 0
  //   wihb  bf16               @ 201,326,592
  //   whhp  packed bf16        @ 202,899,456
  //   woutb bf16               @ 204,472,320
  //   mask8 u8                 @ 204,996,608
  //   hTbuf f32 [256][512]     @ 205,062,144
  //   flags u32[128*32]        @ 205,586,432  (16 KB, zeroed per launch)
  //   xch   [16][2][16][512]bf @ 205,602,816  (512 KB)
  char* ws = (char*)d_ws;
  ushort_t* xi    = (ushort_t*)(ws);
  ushort_t* wihb  = (ushort_t*)(ws + 201326592);
  ushort_t* whhp  = (ushort_t*)(ws + 202899456);
  ushort_t* woutb = (ushort_t*)(ws + 204472320);
  unsigned char* mask8 = (unsigned char*)(ws + 204996608);
  float*    hTbuf = (float*)(ws + 205062144);
  uint_t*   flags = (uint_t*)(ws + 205586432);
  char*     xch   = (char*)(ws + 205602816);

  float* out1 = (float*)d_out;                       // output [N,T,H] f32
  float* out2 = out1 + (size_t)NB * TT * HH;         // hx_out [N,T,H] f32
  ushort_t* hsb = (ushort_t*)out2;  // hs bf16 scratch until bcast overwrites

  hipMemsetAsync(flags, 0, 128 * 32 * sizeof(uint_t), stream);
  mask_detect_kernel<<<1, 1024, 0, stream>>>(isinit, mask8);
  cvt_f2bf<<<768, 256, 0, stream>>>(Wih, wihb, GG * II / 4);
  cvt_f2bf<<<256, 256, 0, stream>>>(Wout, woutb, HH * HH / 4);
  pack_whh<<<384, 256, 0, stream>>>(Whh, whhp);

  dim3 g1(512, 12);  // M/128 x 3H/128
  gemm_bt<1, 0><<<g1, 256, 0, stream>>>((const void*)x, wihb, bih, (void*)xi, GG);

  gru_rec<<<128, 256, 0, stream>>>(xi, whhp, hx, bhh, mask8, hsb, hTbuf,
                                   xch, flags);

  dim3 g3(512, 4);   // M/128 x H/128
  gemm_bt<0, 1><<<g3, 256, 0, stream>>>((const void*)hsb, woutb, bout, (void*)out1, HH);

  bcast_hT<<<2048, 256, 0, stream>>>(hTbuf, out2);
}